// Round 11
// baseline (171901.416 us; speedup 1.0000x reference)
//
#include <hip/hip_runtime.h>
#include <stdint.h>

typedef unsigned long long ull;

#define LCAP 512u   // per-wave LDS ring entries (power of 2)

static __device__ __forceinline__ ull packkey(float f, int v) {
    uint32_t u = __float_as_uint(f);
    u = (u & 0x80000000u) ? ~u : (u | 0x80000000u);
    return ((ull)u << 32) | (ull)(~(uint32_t)v);
}
static __device__ __forceinline__ unsigned aloadu32(const unsigned* p) {
    return __hip_atomic_load(p, __ATOMIC_RELAXED, __HIP_MEMORY_SCOPE_AGENT);
}

// ---------------- build: pred in-degree into upper 16 bits of word ----------------
__global__ void k_build4(const int* __restrict__ neighs, const float* __restrict__ hier,
                         unsigned* __restrict__ word, long E4, int K) {
    long t = (long)blockIdx.x * blockDim.x + threadIdx.x;
    if (t >= E4) return;
    long e = t * 4;
    int u = (int)(e / K);
    ull ku = packkey(hier[u], u);
    int4 w4 = *(const int4*)(neighs + e);
    int ws[4] = {w4.x, w4.y, w4.z, w4.w};
    #pragma unroll
    for (int j = 0; j < 4; j++) {
        int w = ws[j];
        if (w < 0) continue;
        if (ku > packkey(hier[w], w))
            __hip_atomic_fetch_add(&word[w], 0x10000u, __ATOMIC_RELAXED, __HIP_MEMORY_SCOPE_AGENT);
    }
}
__global__ void k_build1(const int* __restrict__ neighs, const float* __restrict__ hier,
                         unsigned* __restrict__ word, long E, int K) {
    long e = (long)blockIdx.x * blockDim.x + threadIdx.x;
    if (e >= E) return;
    int w = neighs[e];
    if (w < 0) return;
    int u = (int)(e / K);
    if (packkey(hier[u], u) > packkey(hier[w], w))
        __hip_atomic_fetch_add(&word[w], 0x10000u, __ATOMIC_RELAXED, __HIP_MEMORY_SCOPE_AGENT);
}

// ---------------- seeds: PURE SNAPSHOT scan (no edge updates!) ----------------
// word is stable here (build kernel fully retired); push (v, CEN) tickets only.
__global__ void k_seed(const unsigned* __restrict__ word, unsigned* __restrict__ gring,
                       unsigned* __restrict__ gctl, int V) {
    int v = blockIdx.x * blockDim.x + threadIdx.x;
    if (v >= V) return;
    if ((word[v] >> 16) == 0u) {
        unsigned p = atomicAdd(&gctl[1], 1u);
        __hip_atomic_store(&gring[p], ((unsigned)v + 1u) | 0x40000000u,
                           __ATOMIC_RELAXED, __HIP_MEMORY_SCOPE_AGENT);
    }
}

// ---------------- process one decided vertex wave-wide; discoveries via add-returns ----------------
// gctl[0]=ghead  gctl[1]=gtail  gctl[2]=doneCnt
// MUST be entered with the FULL wave active (all 64 lanes).
static __device__ __forceinline__ void process_v(
    int v, bool cen, int lane,
    const int* __restrict__ neighs, const float* __restrict__ hier,
    unsigned* __restrict__ word, int K,
    unsigned* lring, unsigned& lh, unsigned& lt,
    unsigned* __restrict__ gring, unsigned* __restrict__ gctl)
{
    ull kv = packkey(hier[v], v);
    const int* row = neighs + (size_t)v * (size_t)K;
    for (int k0 = 0; k0 < K; k0 += 64) {
        int k = k0 + lane;
        int w = (k < K) ? row[k] : -1;
        bool lower = false;
        if (w >= 0) lower = kv > packkey(hier[w], w);
        unsigned old = 0;
        if (lower)
            old = __hip_atomic_fetch_add(&word[w], cen ? 0xFFFF0001u : 0xFFFF0000u,
                                         __ATOMIC_RELAXED, __HIP_MEMORY_SCOPE_AGENT);
        unsigned oldp = old >> 16, oldc = old & 0xFFFFu;
        bool cAbs = lower && cen && (oldc == 0u);                  // unique first-center arrival
        bool cCen = lower && !cen && (oldp == 1u) && (oldc == 0u); // unique last release, no centers
        bool want = cAbs || cCen;
        ull wm = __ballot(want);
        if (!wm) continue;
        unsigned ent = want ? (((unsigned)w + 1u) | (cCen ? 0x40000000u : 0u)) : 0u;
        unsigned space = LCAP - (lt - lh);
        unsigned pre = (unsigned)__popcll(wm & ((1ull << lane) - 1ull));
        unsigned nloc = min((unsigned)__popcll(wm), space);
        bool toL = want && (pre < space);
        if (toL) lring[(lt + pre) & (LCAP - 1u)] = ent;
        lt += nloc;
        ull gm = __ballot(want && !toL);
        if (gm) {
            int leader = __ffsll((unsigned long long)gm) - 1;
            unsigned base = 0;
            if (lane == leader)
                base = atomicAdd(&gctl[1], (unsigned)__popcll(gm));
            base = (unsigned)__shfl((int)base, leader);
            unsigned gpre = (unsigned)__popcll(gm & ((1ull << lane) - 1ull));
            if (want && !toL)
                __hip_atomic_store(&gring[base + gpre], ent,
                                   __ATOMIC_RELAXED, __HIP_MEMORY_SCOPE_AGENT);
        }
    }
    if (lane == 0)
        __hip_atomic_fetch_add(&gctl[2], 1u, __ATOMIC_RELAXED, __HIP_MEMORY_SCOPE_AGENT);
}

// ---------------- propagate: LDS-ring chain walk + global-ring work stealing ----------------
// ALL control decisions are lane-0-read + broadcast: every branch wave-uniform;
// process_v always runs with the full wave active.
__global__ __launch_bounds__(256, 4)
void k_propagate(const int* __restrict__ neighs, const float* __restrict__ hier,
                 unsigned* __restrict__ word, unsigned* __restrict__ gring,
                 unsigned* __restrict__ gctl, int V, int K) {
    __shared__ unsigned lrs[4][LCAP];
    const int lane = threadIdx.x & 63;
    unsigned* lring = lrs[threadIdx.x >> 6];
    unsigned lh = 0, lt = 0;   // wave-uniform ring indices
    long sweeps = 0;
    while (true) {
        if (lh != lt) {                       // chain fast path: our own ring (uniform)
            unsigned ent = lring[lh & (LCAP - 1u)];
            lh++;
            int v = (int)(ent & 0x3FFFFFFFu) - 1;
            process_v(v, (ent & 0x40000000u) != 0u, lane, neighs, hier, word, K,
                      lring, lh, lt, gring, gctl);
            sweeps = 0;
            continue;
        }
        // lane 0 makes all decisions; broadcast for uniform control flow
        int action = 0;        // 0=idle, 1=process ent, 2=done
        unsigned ent = 0;
        if (lane == 0) {
            unsigned h = aloadu32(&gctl[0]);
            unsigned t2 = aloadu32(&gctl[1]);
            if (h < t2) {
                unsigned exp = h;
                if (__hip_atomic_compare_exchange_strong(
                        &gctl[0], &exp, h + 1u,
                        __ATOMIC_RELAXED, __ATOMIC_RELAXED, __HIP_MEMORY_SCOPE_AGENT)) {
                    long spin = 0;
                    unsigned e2 = 0;
                    do {
                        e2 = aloadu32(&gring[h]);
                    } while (e2 == 0u && ++spin < 2000000L);
                    if (e2) { action = 1; ent = e2; }
                }
            } else if (aloadu32(&gctl[2]) >= (unsigned)V) {
                action = 2;
            }
        }
        action = __shfl(action, 0);
        ent = (unsigned)__shfl((int)ent, 0);
        if (action == 1) {
            int v = (int)(ent & 0x3FFFFFFFu) - 1;
            process_v(v, (ent & 0x40000000u) != 0u, lane, neighs, hier, word, K,
                      lring, lh, lt, gring, gctl);
            sweeps = 0;
            continue;
        }
        if (action == 2) break;               // all V processed exactly once
        __builtin_amdgcn_s_sleep(8);
        if (++sweeps > 3000000L) break;       // safety net: never hang the bench
    }
}

// ---------------- epilogue: absorber identity = max key over centers containing w ----------------
__global__ void k_absorb(const int* __restrict__ neighs, const float* __restrict__ hier,
                         const unsigned* __restrict__ word, ull* __restrict__ best,
                         int V, int K, int NW) {
    const int gtid = blockIdx.x * blockDim.x + threadIdx.x;
    const int wv = gtid >> 6, lane = gtid & 63;
    const int G = (V + 63) >> 6;
    for (int g = wv; g < G; g += NW) {
        int v = (g << 6) + lane;
        bool cenv = (v < V) && ((word[v] & 0xFFFFu) == 0u);
        ull cm = __ballot(cenv);
        while (cm) {
            int l = __ffsll((unsigned long long)cm) - 1;
            cm &= cm - 1;
            int u = (g << 6) + l;
            ull ku = packkey(hier[u], u);
            const int* row = neighs + (size_t)u * (size_t)K;
            for (int k0 = 0; k0 < K; k0 += 64) {
                int k = k0 + lane;
                int w = (k < K) ? row[k] : -1;
                if (w >= 0 && ku > packkey(hier[w], w))
                    __hip_atomic_fetch_max(&best[w], ku,
                                           __ATOMIC_RELAXED, __HIP_MEMORY_SCOPE_AGENT);
            }
        }
    }
}

// ---------------- compact centers per segment ----------------
__global__ void k_compact(const float* __restrict__ hier,
                          const unsigned* __restrict__ word,
                          const int* __restrict__ row_splits,
                          ull* __restrict__ segKeys,
                          int* __restrict__ segIds,
                          int* __restrict__ counters,
                          int V, int NSEG) {
    int v = blockIdx.x * blockDim.x + threadIdx.x;
    if (v >= V) return;
    if ((word[v] & 0xFFFFu) != 0u) return;   // center <=> no center in-edges
    int s = 0;
    while (s + 1 < NSEG && v >= row_splits[s + 1]) s++;
    int p = atomicAdd(&counters[s], 1);
    int base = row_splits[s];
    segKeys[base + p] = packkey(hier[v], v);
    segIds[base + p]  = v;
}

// ---------------- rs prefix (tiny) ----------------
__global__ void k_rs(const int* __restrict__ counters,
                     int* __restrict__ rsBase,
                     int* __restrict__ rs_out,
                     int NSEG) {
    if (blockIdx.x == 0 && threadIdx.x == 0) {
        int acc = 0;
        rs_out[0] = 0;
        for (int s = 0; s < NSEG; s++) {
            rsBase[s] = acc;
            acc += counters[s];
            rs_out[s + 1] = acc;
        }
    }
}

// ---------------- rank centers -> cid, sel ----------------
__global__ void k_rank(const ull* __restrict__ segKeys,
                       const int* __restrict__ segIds,
                       const int* __restrict__ counters,
                       const int* __restrict__ rsBase,
                       const int* __restrict__ row_splits,
                       int* __restrict__ cidOf,
                       int* __restrict__ sel_out,
                       int V, int NSEG) {
    int t = blockIdx.x * blockDim.x + threadIdx.x;
    if (t >= V) return;
    int s = 0;
    while (s + 1 < NSEG && t >= row_splits[s + 1]) s++;
    int base = row_splits[s];
    int j = t - base;
    int cnt = counters[s];
    if (j >= cnt) return;
    ull mk = segKeys[t];
    int r = 0;
    for (int i = 0; i < cnt; i++) r += (segKeys[base + i] > mk) ? 1 : 0;
    int cid = rsBase[s] + r;
    int v = segIds[t];
    cidOf[v] = cid;
    sel_out[cid] = v;
}

// ---------------- final cluster assignment ----------------
__global__ void k_assign(const ull* __restrict__ best,
                         const int* __restrict__ cidOf,
                         int* __restrict__ clus_out,
                         int V) {
    int v = blockIdx.x * blockDim.x + threadIdx.x;
    if (v >= V) return;
    ull b = best[v];
    int c;
    if (b == 0ull) {
        c = cidOf[v];                                   // center (never receives a max)
    } else {
        uint32_t a = ~(uint32_t)(b & 0xFFFFFFFFull);    // absorber global index
        c = cidOf[a];
    }
    clus_out[v] = c;
}

extern "C" void kernel_launch(void* const* d_in, const int* in_sizes, int n_in,
                              void* d_out, int out_size, void* d_ws, size_t ws_size,
                              hipStream_t stream) {
    const int*   neighs     = (const int*)d_in[0];
    const float* hier       = (const float*)d_in[1];
    const int*   row_splits = (const int*)d_in[2];

    const int V    = in_sizes[1];
    const int K    = in_sizes[0] / V;
    const int NSEG = in_sizes[2] - 1;
    const long E   = (long)V * (long)K;

    int* out      = (int*)d_out;
    int* sel_out  = out;
    int* rs_out   = out + V;
    int* clus_out = out + V + NSEG + 1;

    // ws: [best 8V][word 4V][gring 4(V+64)][ctrl 256][segKeys 8V][segIds 4V][cidOf 4V]
    char* w = (char*)d_ws;
    ull*      best    = (ull*)(w);
    unsigned* word    = (unsigned*)(w + (size_t)8 * V);
    unsigned* gring   = (unsigned*)(w + (size_t)12 * V);
    size_t ctrlOff    = ((size_t)16 * V + 256 + 7) & ~(size_t)7;
    unsigned* gctl    = (unsigned*)(w + ctrlOff);           // [0]=ghead [1]=gtail [2]=done
    int*      cnts    = (int*)(w + ctrlOff + 64);
    int*      rsBase  = (int*)(w + ctrlOff + 128);
    size_t segOff     = ctrlOff + 256;
    ull*      segKeys = (ull*)(w + segOff);
    int*      segIds  = (int*)(w + segOff + (size_t)8 * V);
    int*      cidOf   = (int*)(w + segOff + (size_t)12 * V);

    const int B  = 256;
    const int gV = (V + B - 1) / B;

    (void)hipMemsetAsync(w, 0, segOff, stream);               // best, word, gring, ctrl
    (void)hipMemsetAsync(sel_out, 0xFF, (size_t)4 * V, stream);

    if ((K & 3) == 0) {
        long E4 = E / 4;
        k_build4<<<(int)((E4 + B - 1) / B), B, 0, stream>>>(neighs, hier, word, E4, K);
    } else {
        k_build1<<<(int)((E + B - 1) / B), B, 0, stream>>>(neighs, hier, word, E, K);
    }

    const int PB = 1024;                 // 4 blocks/CU guaranteed co-resident
    const int NW = PB * B / 64;          // 4096 waves
    k_seed<<<gV, B, 0, stream>>>(word, gring, gctl, V);
    k_propagate<<<PB, B, 0, stream>>>(neighs, hier, word, gring, gctl, V, K);

    k_absorb<<<PB, B, 0, stream>>>(neighs, hier, word, best, V, K, NW);
    k_compact<<<gV, B, 0, stream>>>(hier, word, row_splits, segKeys, segIds, cnts, V, NSEG);
    k_rs<<<1, 64, 0, stream>>>(cnts, rsBase, rs_out, NSEG);
    k_rank<<<gV, B, 0, stream>>>(segKeys, segIds, cnts, rsBase, row_splits,
                                 cidOf, sel_out, V, NSEG);
    k_assign<<<gV, B, 0, stream>>>(best, cidOf, clus_out, V);
}

// Round 12
// 42970.181 us; speedup vs baseline: 4.0005x; 4.0005x over previous
//
#include <hip/hip_runtime.h>
#include <stdint.h>

typedef unsigned long long ull;

#define NRING 16

static __device__ __forceinline__ ull packkey(float f, int v) {
    uint32_t u = __float_as_uint(f);
    u = (u & 0x80000000u) ? ~u : (u | 0x80000000u);
    return ((ull)u << 32) | (ull)(~(uint32_t)v);
}
static __device__ __forceinline__ unsigned aloadu32(const unsigned* p) {
    return __hip_atomic_load(p, __ATOMIC_RELAXED, __HIP_MEMORY_SCOPE_AGENT);
}
static __device__ __forceinline__ int aloadi(const int* p) {
    return __hip_atomic_load(p, __ATOMIC_RELAXED, __HIP_MEMORY_SCOPE_AGENT);
}
static __device__ __forceinline__ void astore(unsigned* p, unsigned v) {
    __hip_atomic_store(p, v, __ATOMIC_RELAXED, __HIP_MEMORY_SCOPE_AGENT);
}

// ---------------- build: in-degree of absorption DAG into pred field (word>>16) ----------------
__global__ void k_build4(const int* __restrict__ neighs, const float* __restrict__ hier,
                         unsigned* __restrict__ word, long E4, int K) {
    long t = (long)blockIdx.x * blockDim.x + threadIdx.x;
    if (t >= E4) return;
    long e = t * 4;
    int u = (int)(e / K);
    ull ku = packkey(hier[u], u);
    int4 w4 = *(const int4*)(neighs + e);
    int ws[4] = {w4.x, w4.y, w4.z, w4.w};
    #pragma unroll
    for (int j = 0; j < 4; j++) {
        int w = ws[j];
        if (w < 0) continue;
        if (ku > packkey(hier[w], w))
            __hip_atomic_fetch_add(&word[w], 0x10000u, __ATOMIC_RELAXED, __HIP_MEMORY_SCOPE_AGENT);
    }
}
__global__ void k_build1(const int* __restrict__ neighs, const float* __restrict__ hier,
                         unsigned* __restrict__ word, long E, int K) {
    long e = (long)blockIdx.x * blockDim.x + threadIdx.x;
    if (e >= E) return;
    int w = neighs[e];
    if (w < 0) return;
    int u = (int)(e / K);
    if (packkey(hier[u], u) > packkey(hier[w], w))
        __hip_atomic_fetch_add(&word[w], 0x10000u, __ATOMIC_RELAXED, __HIP_MEMORY_SCOPE_AGENT);
}

// ---------------- seeds: snapshot scan (word stable between kernels); batched ring append ----------------
__global__ void k_seed(const unsigned* __restrict__ word, unsigned* __restrict__ ring,
                       int* __restrict__ ctl, int V, unsigned RCAP) {
    int v = blockIdx.x * blockDim.x + threadIdx.x;
    int lane = threadIdx.x & 63;
    bool sd = (v < V) && ((word[v] >> 16) == 0u);
    ull m = __ballot(sd);
    if (!m) return;
    int r = (v >> 6) & (NRING - 1);                 // uniform per 64-group
    int leader = __ffsll((unsigned long long)m) - 1;
    int n = __popcll(m);
    unsigned base = 0;
    if (lane == leader) base = (unsigned)atomicAdd(&ctl[r * 32], n);
    base = (unsigned)__shfl((int)base, leader);
    unsigned pre = (unsigned)__popcll(m & ((1ull << lane) - 1ull));
    if (sd) astore(&ring[(unsigned)r * RCAP + base + pre], ((unsigned)v + 1u) | 0x40000000u);
}

// ---------------- process one decided vertex wave-wide (FULL wave active) ----------------
// Returns the continuation entry (first triggered child) or 0; spills the rest.
static __device__ __forceinline__ unsigned proc(
    unsigned ent, int lane, unsigned& rot,
    const int* __restrict__ neighs, const float* __restrict__ hier,
    unsigned* __restrict__ word, int K,
    unsigned* __restrict__ ring, unsigned RCAP, int* __restrict__ ctl)
{
    int v = (int)(ent & 0x3FFFFFFFu) - 1;
    bool cen = (ent & 0x40000000u) != 0u;
    ull kv = packkey(hier[v], v);
    const int* row = neighs + (size_t)v * (size_t)K;
    unsigned cont = 0;
    for (int k0 = 0; k0 < K; k0 += 64) {
        int k = k0 + lane;
        int w = (k < K) ? row[k] : -1;
        bool lower = (w >= 0) && (kv > packkey(hier[w], w));
        unsigned old = 0;
        if (lower)
            old = __hip_atomic_fetch_add(&word[w], cen ? 0xFFFF0001u : 0xFFFF0000u,
                                         __ATOMIC_RELAXED, __HIP_MEMORY_SCOPE_AGENT);
        bool cAbs = lower && cen && ((old & 0xFFFFu) == 0u);                    // unique 1st center arrival
        bool cCen = lower && !cen && ((old >> 16) == 1u) && ((old & 0xFFFFu) == 0u); // unique last release
        bool want = cAbs || cCen;
        ull wm = __ballot(want);
        if (!wm) continue;
        unsigned ew = ((unsigned)w + 1u) | (cCen ? 0x40000000u : 0u);
        ull sm = wm;
        if (cont == 0u) {                           // take first child as chain continuation
            int fl = __ffsll((unsigned long long)wm) - 1;
            cont = (unsigned)__shfl((int)ew, fl);
            sm = wm & ~(1ull << fl);
        }
        if (sm) {                                   // spill the rest to a rotating ring
            int r = (int)((rot++) & (NRING - 1u));
            int leader = __ffsll((unsigned long long)sm) - 1;
            unsigned n = (unsigned)__popcll(sm);
            unsigned base = 0;
            if (lane == leader) base = (unsigned)atomicAdd(&ctl[r * 32], (int)n);
            base = (unsigned)__shfl((int)base, leader);
            unsigned pre = (unsigned)__popcll(sm & ((1ull << lane) - 1ull));
            if ((sm >> lane) & 1ull)
                astore(&ring[(unsigned)r * RCAP + base + pre], ew);
        }
    }
    return cont;
}

// ---------------- propagate: chain-walk + distributed ring stealing; no global counters ----------------
__global__ __launch_bounds__(256, 4)
void k_propagate(const int* __restrict__ neighs, const float* __restrict__ hier,
                 unsigned* __restrict__ word, unsigned* __restrict__ ring,
                 int* __restrict__ ctl, int V, int K, unsigned RCAP) {
    const int gtid = blockIdx.x * blockDim.x + threadIdx.x;
    const int wv = gtid >> 6, lane = gtid & 63;
    unsigned rot = (unsigned)wv * 7u + 1u;
    unsigned cont = 0;
    int cr = 0, cn = 0; int ch = 0;                 // batch-claim state (wave-uniform)
    int empties = 0;
    long sweeps = 0;

    while (true) {
        if (cont) {                                 // chain fast path
            cont = proc(cont, lane, rot, neighs, hier, word, K, ring, RCAP, ctl);
            continue;
        }
        if (cn > 0) {                               // drain our claimed batch
            unsigned e = 0;
            if (lane == 0) {
                long sp = 0;
                do { e = aloadu32(&ring[(unsigned)cr * RCAP + (unsigned)ch]); }
                while (!e && ++sp < 200000L);
            }
            e = (unsigned)__shfl((int)e, 0);
            ch++; cn--;
            if (e) cont = e;
            continue;
        }
        // scan rings (lanes 0..15 read one head/tail pair each; different cache lines)
        int t = 0, h = 0;
        if (lane < NRING) { t = aloadi(&ctl[lane * 32]); h = aloadi(&ctl[lane * 32 + 16]); }
        ull ne = __ballot(lane < NRING && t > h);
        if (ne) {
            empties = 0;
            int r = 0;
            for (int i = 0; i < NRING; i++) {       // uniform: rot, ne uniform
                int c = (int)((rot + (unsigned)i) & (NRING - 1u));
                if ((ne >> c) & 1ull) { r = c; break; }
            }
            rot += 3u;
            int act = 0, hh = 0, n = 0;
            if (lane == 0) {
                hh = aloadi(&ctl[r * 32 + 16]);
                int tt = aloadi(&ctl[r * 32]);
                if (tt > hh) {
                    n = tt - hh; if (n > 4) n = 4;
                    int exp = hh;
                    if (__hip_atomic_compare_exchange_strong(
                            &ctl[r * 32 + 16], &exp, hh + n,
                            __ATOMIC_RELAXED, __ATOMIC_RELAXED, __HIP_MEMORY_SCOPE_AGENT))
                        act = 1;
                }
            }
            act = __shfl(act, 0);
            if (act) {
                cr = r; ch = __shfl(hh, 0); cn = __shfl(n, 0);
                sweeps = 0;
                continue;
            }
            __builtin_amdgcn_s_sleep(2);            // lost claim race; brief backoff
            if (++sweeps > 2000000L) break;
            continue;
        }
        if (++empties >= 16) break;                 // all rings empty repeatedly -> exit
        __builtin_amdgcn_s_sleep(32);
        if (++sweeps > 2000000L) break;             // safety net
    }
}

// ---------------- epilogue: absorber identity = max key over centers containing w ----------------
__global__ void k_absorb(const int* __restrict__ neighs, const float* __restrict__ hier,
                         const unsigned* __restrict__ word, ull* __restrict__ best,
                         int V, int K, int NW) {
    const int gtid = blockIdx.x * blockDim.x + threadIdx.x;
    const int wv = gtid >> 6, lane = gtid & 63;
    const int G = (V + 63) >> 6;
    for (int g = wv; g < G; g += NW) {
        int v = (g << 6) + lane;
        bool cenv = (v < V) && ((word[v] & 0xFFFFu) == 0u);
        ull cm = __ballot(cenv);
        while (cm) {
            int l = __ffsll((unsigned long long)cm) - 1;
            cm &= cm - 1;
            int u = (g << 6) + l;
            ull ku = packkey(hier[u], u);
            const int* row = neighs + (size_t)u * (size_t)K;
            for (int k0 = 0; k0 < K; k0 += 64) {
                int k = k0 + lane;
                int w = (k < K) ? row[k] : -1;
                if (w >= 0 && ku > packkey(hier[w], w))
                    __hip_atomic_fetch_max(&best[w], ku,
                                           __ATOMIC_RELAXED, __HIP_MEMORY_SCOPE_AGENT);
            }
        }
    }
}

// ---------------- compact centers per segment (ballot-batched counter adds) ----------------
__global__ void k_compact(const float* __restrict__ hier,
                          const unsigned* __restrict__ word,
                          const int* __restrict__ row_splits,
                          ull* __restrict__ segKeys,
                          int* __restrict__ segIds,
                          int* __restrict__ counters,
                          int V, int NSEG) {
    int v = blockIdx.x * blockDim.x + threadIdx.x;
    int lane = threadIdx.x & 63;
    bool isc = (v < V) && ((word[v] & 0xFFFFu) == 0u);
    int s = 0;
    if (isc) { while (s + 1 < NSEG && v >= row_splits[s + 1]) s++; }
    if (!__any(isc)) return;
    for (int s0 = 0; s0 < NSEG; s0++) {
        ull ms = __ballot(isc && s == s0);
        if (!ms) continue;
        int leader = __ffsll((unsigned long long)ms) - 1;
        int n = __popcll(ms);
        unsigned base = 0;
        if (lane == leader) base = (unsigned)atomicAdd(&counters[s0], n);
        base = (unsigned)__shfl((int)base, leader);
        unsigned pre = (unsigned)__popcll(ms & ((1ull << lane) - 1ull));
        if (isc && s == s0) {
            int slot = row_splits[s0] + (int)(base + pre);
            segKeys[slot] = packkey(hier[v], v);
            segIds[slot] = v;
        }
    }
}

// ---------------- rs prefix (tiny) ----------------
__global__ void k_rs(const int* __restrict__ counters,
                     int* __restrict__ rsBase,
                     int* __restrict__ rs_out,
                     int NSEG) {
    if (blockIdx.x == 0 && threadIdx.x == 0) {
        int acc = 0;
        rs_out[0] = 0;
        for (int s = 0; s < NSEG; s++) {
            rsBase[s] = acc;
            acc += counters[s];
            rs_out[s + 1] = acc;
        }
    }
}

// ---------------- rank centers -> cid, sel ----------------
__global__ void k_rank(const ull* __restrict__ segKeys,
                       const int* __restrict__ segIds,
                       const int* __restrict__ counters,
                       const int* __restrict__ rsBase,
                       const int* __restrict__ row_splits,
                       int* __restrict__ cidOf,
                       int* __restrict__ sel_out,
                       int V, int NSEG) {
    int t = blockIdx.x * blockDim.x + threadIdx.x;
    if (t >= V) return;
    int s = 0;
    while (s + 1 < NSEG && t >= row_splits[s + 1]) s++;
    int base = row_splits[s];
    int j = t - base;
    int cnt = counters[s];
    if (j >= cnt) return;
    ull mk = segKeys[t];
    int r = 0;
    for (int i = 0; i < cnt; i++) r += (segKeys[base + i] > mk) ? 1 : 0;
    int cid = rsBase[s] + r;
    int v = segIds[t];
    cidOf[v] = cid;
    sel_out[cid] = v;
}

// ---------------- final cluster assignment ----------------
__global__ void k_assign(const ull* __restrict__ best,
                         const int* __restrict__ cidOf,
                         int* __restrict__ clus_out,
                         int V) {
    int v = blockIdx.x * blockDim.x + threadIdx.x;
    if (v >= V) return;
    ull b = best[v];
    int c;
    if (b == 0ull) {
        c = cidOf[v];                                   // center (never receives a max)
    } else {
        uint32_t a = ~(uint32_t)(b & 0xFFFFFFFFull);    // absorber global index
        c = cidOf[a];
    }
    clus_out[v] = c;
}

extern "C" void kernel_launch(void* const* d_in, const int* in_sizes, int n_in,
                              void* d_out, int out_size, void* d_ws, size_t ws_size,
                              hipStream_t stream) {
    const int*   neighs     = (const int*)d_in[0];
    const float* hier       = (const float*)d_in[1];
    const int*   row_splits = (const int*)d_in[2];

    const int V    = in_sizes[1];
    const int K    = in_sizes[0] / V;
    const int NSEG = in_sizes[2] - 1;
    const long E   = (long)V * (long)K;

    unsigned RCAP = 1024;
    while (RCAP < (unsigned)(V / 8 + 8192)) RCAP <<= 1;   // per-ring capacity, no wraparound

    int* out      = (int*)d_out;
    int* sel_out  = out;
    int* rs_out   = out + V;
    int* clus_out = out + V + NSEG + 1;

    // ws: [best 8V][word 4V][ctl 2048][cnts 128][rsBase 128][pad->4KB][ring 4*16*RCAP][segKeys 8V][segIds 4V][cidOf 4V]
    char* w = (char*)d_ws;
    ull*      best   = (ull*)(w);
    unsigned* word   = (unsigned*)(w + (size_t)8 * V);
    size_t ctlOff    = (size_t)12 * V;
    int*      ctl    = (int*)(w + ctlOff);                    // 16 rings * 128B
    int*      cnts   = (int*)(w + ctlOff + 2048);
    int*      rsBase = (int*)(w + ctlOff + 2048 + 128);
    size_t ringOff   = ctlOff + 4096;
    unsigned* ring   = (unsigned*)(w + ringOff);
    size_t segOff    = ringOff + (size_t)4 * NRING * RCAP;
    ull*      segKeys = (ull*)(w + segOff);
    int*      segIds  = (int*)(w + segOff + (size_t)8 * V);
    int*      cidOf   = (int*)(w + segOff + (size_t)12 * V);

    const int B  = 256;
    const int gV = (V + B - 1) / B;

    // zero: best, word, ctl/cnts, ring (ring MUST be cleared every call: stale nonzero
    // slots from a previous replay would be consumed as bogus entries)
    (void)hipMemsetAsync(w, 0, segOff, stream);
    (void)hipMemsetAsync(sel_out, 0xFF, (size_t)4 * V, stream);

    if ((K & 3) == 0) {
        long E4 = E / 4;
        k_build4<<<(int)((E4 + B - 1) / B), B, 0, stream>>>(neighs, hier, word, E4, K);
    } else {
        k_build1<<<(int)((E + B - 1) / B), B, 0, stream>>>(neighs, hier, word, E, K);
    }

    k_seed<<<gV, B, 0, stream>>>(word, ring, ctl, V, RCAP);

    const int PB = 1024;                 // 4 blocks/CU co-resident
    const int NW = PB * B / 64;          // 4096 waves
    k_propagate<<<PB, B, 0, stream>>>(neighs, hier, word, ring, ctl, V, K, RCAP);

    k_absorb<<<PB, B, 0, stream>>>(neighs, hier, word, best, V, K, NW);
    k_compact<<<gV, B, 0, stream>>>(hier, word, row_splits, segKeys, segIds, cnts, V, NSEG);
    k_rs<<<1, 64, 0, stream>>>(cnts, rsBase, rs_out, NSEG);
    k_rank<<<gV, B, 0, stream>>>(segKeys, segIds, cnts, rsBase, row_splits,
                                 cidOf, sel_out, V, NSEG);
    k_assign<<<gV, B, 0, stream>>>(best, cidOf, clus_out, V);
}

// Round 13
// 1756.709 us; speedup vs baseline: 97.8543x; 24.4606x over previous
//
#include <hip/hip_runtime.h>
#include <stdint.h>

typedef unsigned long long ull;

static __device__ __forceinline__ ull packkey(float f, int v) {
    uint32_t u = __float_as_uint(f);
    u = (u & 0x80000000u) ? ~u : (u | 0x80000000u);
    return ((ull)u << 32) | (ull)(~(uint32_t)v);
}
static __device__ __forceinline__ unsigned aloadu32(const unsigned* p) {
    return __hip_atomic_load(p, __ATOMIC_RELAXED, __HIP_MEMORY_SCOPE_AGENT);
}

// ---------------- build: in-degree of absorption DAG into pred field (word>>16) ----------------
__global__ void k_build4(const int* __restrict__ neighs, const float* __restrict__ hier,
                         unsigned* __restrict__ word, long E4, int K) {
    long t = (long)blockIdx.x * blockDim.x + threadIdx.x;
    if (t >= E4) return;
    long e = t * 4;
    int u = (int)(e / K);
    ull ku = packkey(hier[u], u);
    int4 w4 = *(const int4*)(neighs + e);
    int ws[4] = {w4.x, w4.y, w4.z, w4.w};
    #pragma unroll
    for (int j = 0; j < 4; j++) {
        int w = ws[j];
        if (w < 0) continue;
        if (ku > packkey(hier[w], w))
            atomicAdd(&word[w], 0x10000u);     // fire-and-forget
    }
}
__global__ void k_build1(const int* __restrict__ neighs, const float* __restrict__ hier,
                         unsigned* __restrict__ word, long E, int K) {
    long e = (long)blockIdx.x * blockDim.x + threadIdx.x;
    if (e >= E) return;
    int w = neighs[e];
    if (w < 0) return;
    int u = (int)(e / K);
    if (packkey(hier[u], u) > packkey(hier[w], w))
        atomicAdd(&word[w], 0x10000u);
}

// ---------------- propagation: owner polls word; fire-and-forget fused adds ----------------
// word[v] = pred<<16 | cenCount.  Decisions (owner-side, single load, NO fences):
//   ABSORBED : cen>0   (first center arrival decides; no need to wait for pred)
//   CENTER   : word==0 (pred==0 & cen==0; final: every higher in-neighbor was processed
//              and its cen contribution, fused in the SAME atomic as its pred release,
//              has already landed)
static __device__ __forceinline__ bool sweep_group(
    int gb, bool pend, int lane,
    const int* __restrict__ neighs, const float* __restrict__ hier,
    unsigned* __restrict__ word, int K, bool& found)
{
    if (!__any(pend)) return pend;
    int v = gb + lane;
    unsigned wd = 0x7FFF0000u;
    if (pend) wd = aloadu32(&word[v]);
    bool absn = pend && ((wd & 0xFFFFu) != 0u);
    bool cenn = pend && (wd == 0u);
    bool dec = absn || cenn;
    ull mdec = __ballot(dec);
    if (!mdec) return pend;
    found = true;
    ull mcen = __ballot(cenn);

    while (mdec) {
        int ls[4];
        int nb = 0;
        while (nb < 4 && mdec) {
            int l = __ffsll((unsigned long long)mdec) - 1;
            mdec &= mdec - 1;
            ls[nb++] = l;
        }
        #pragma unroll
        for (int j = nb; j < 4; j++) ls[j] = -1;

        int vv[4]; ull kv[4]; unsigned dj[4];
        #pragma unroll
        for (int j = 0; j < 4; j++) {
            vv[j] = 0; kv[j] = 0; dj[j] = 0;
            if (ls[j] >= 0) {
                vv[j] = gb + ls[j];
                dj[j] = ((mcen >> ls[j]) & 1ull) ? 0xFFFF0001u : 0xFFFF0000u;
                kv[j] = packkey(hier[vv[j]], vv[j]);
            }
        }
        for (int k0 = 0; k0 < K; k0 += 64) {
            int k = k0 + lane;
            bool kok = k < K;
            #pragma unroll
            for (int j = 0; j < 4; j++) {
                if (ls[j] >= 0 && kok) {
                    int w = neighs[(size_t)vv[j] * (size_t)K + k];
                    if (w >= 0 && kv[j] > packkey(hier[w], w))
                        atomicAdd(&word[w], dj[j]);   // fused pred-release + cen-mark
                }
            }
        }
    }
    return pend && !dec;
}

__global__ __launch_bounds__(256, 4)
void k_propagate(const int* __restrict__ neighs, const float* __restrict__ hier,
                 unsigned* __restrict__ word, int V, int K, int nwaves) {
    const int gtid = blockIdx.x * blockDim.x + threadIdx.x;
    const int wv = gtid >> 6, lane = gtid & 63;
    const int G = (V + 63) >> 6;
    int gb0 = (wv < G) ? (wv << 6) : -1;
    int g1 = wv + nwaves;
    int gb1 = (g1 < G) ? (g1 << 6) : -1;
    bool p0 = gb0 >= 0 && gb0 + lane < V;
    bool p1 = gb1 >= 0 && gb1 + lane < V;

    long sweeps = 0;
    while (__any(p0 || p1)) {
        bool found = false;
        p0 = sweep_group(gb0, p0, lane, neighs, hier, word, K, found);
        p1 = sweep_group(gb1, p1, lane, neighs, hier, word, K, found);
        if (found) {
            sweeps = 0;
        } else {
            __builtin_amdgcn_s_sleep(2);
            if (++sweeps > 1000000L) break;   // safety net: never hang the bench
        }
    }
}

// ---------------- epilogue: absorber identity = max key over centers containing w ----------------
__global__ void k_absorb(const int* __restrict__ neighs, const float* __restrict__ hier,
                         const unsigned* __restrict__ word, ull* __restrict__ best,
                         int V, int K, int NW) {
    const int gtid = blockIdx.x * blockDim.x + threadIdx.x;
    const int wv = gtid >> 6, lane = gtid & 63;
    const int G = (V + 63) >> 6;
    for (int g = wv; g < G; g += NW) {
        int v = (g << 6) + lane;
        bool cenv = (v < V) && ((word[v] & 0xFFFFu) == 0u);
        ull cm = __ballot(cenv);
        while (cm) {
            int l = __ffsll((unsigned long long)cm) - 1;
            cm &= cm - 1;
            int u = (g << 6) + l;
            ull ku = packkey(hier[u], u);
            const int* row = neighs + (size_t)u * (size_t)K;
            for (int k0 = 0; k0 < K; k0 += 64) {
                int k = k0 + lane;
                int w = (k < K) ? row[k] : -1;
                if (w >= 0 && ku > packkey(hier[w], w))
                    atomicMax(&best[w], ku);
            }
        }
    }
}

// ---------------- compact centers per segment (ballot-batched) ----------------
__global__ void k_compact(const float* __restrict__ hier,
                          const unsigned* __restrict__ word,
                          const int* __restrict__ row_splits,
                          ull* __restrict__ segKeys,
                          int* __restrict__ segIds,
                          int* __restrict__ counters,
                          int V, int NSEG) {
    int v = blockIdx.x * blockDim.x + threadIdx.x;
    int lane = threadIdx.x & 63;
    bool isc = (v < V) && ((word[v] & 0xFFFFu) == 0u);
    int s = 0;
    if (isc) { while (s + 1 < NSEG && v >= row_splits[s + 1]) s++; }
    if (!__any(isc)) return;
    for (int s0 = 0; s0 < NSEG; s0++) {
        ull ms = __ballot(isc && s == s0);
        if (!ms) continue;
        int leader = __ffsll((unsigned long long)ms) - 1;
        int n = __popcll(ms);
        unsigned base = 0;
        if (lane == leader) base = (unsigned)atomicAdd(&counters[s0], n);
        base = (unsigned)__shfl((int)base, leader);
        unsigned pre = (unsigned)__popcll(ms & ((1ull << lane) - 1ull));
        if (isc && s == s0) {
            int slot = row_splits[s0] + (int)(base + pre);
            segKeys[slot] = packkey(hier[v], v);
            segIds[slot] = v;
        }
    }
}

// ---------------- rs prefix (tiny) ----------------
__global__ void k_rs(const int* __restrict__ counters,
                     int* __restrict__ rsBase,
                     int* __restrict__ rs_out,
                     int NSEG) {
    if (blockIdx.x == 0 && threadIdx.x == 0) {
        int acc = 0;
        rs_out[0] = 0;
        for (int s = 0; s < NSEG; s++) {
            rsBase[s] = acc;
            acc += counters[s];
            rs_out[s + 1] = acc;
        }
    }
}

// ---------------- rank centers -> cid, sel ----------------
__global__ void k_rank(const ull* __restrict__ segKeys,
                       const int* __restrict__ segIds,
                       const int* __restrict__ counters,
                       const int* __restrict__ rsBase,
                       const int* __restrict__ row_splits,
                       int* __restrict__ cidOf,
                       int* __restrict__ sel_out,
                       int V, int NSEG) {
    int t = blockIdx.x * blockDim.x + threadIdx.x;
    if (t >= V) return;
    int s = 0;
    while (s + 1 < NSEG && t >= row_splits[s + 1]) s++;
    int base = row_splits[s];
    int j = t - base;
    int cnt = counters[s];
    if (j >= cnt) return;
    ull mk = segKeys[t];
    int r = 0;
    for (int i = 0; i < cnt; i++) r += (segKeys[base + i] > mk) ? 1 : 0;
    int cid = rsBase[s] + r;
    int v = segIds[t];
    cidOf[v] = cid;
    sel_out[cid] = v;
}

// ---------------- final cluster assignment ----------------
__global__ void k_assign(const ull* __restrict__ best,
                         const int* __restrict__ cidOf,
                         int* __restrict__ clus_out,
                         int V) {
    int v = blockIdx.x * blockDim.x + threadIdx.x;
    if (v >= V) return;
    ull b = best[v];
    int c;
    if (b == 0ull) {
        c = cidOf[v];                                   // center (never receives a max)
    } else {
        uint32_t a = ~(uint32_t)(b & 0xFFFFFFFFull);    // absorber global index
        c = cidOf[a];
    }
    clus_out[v] = c;
}

extern "C" void kernel_launch(void* const* d_in, const int* in_sizes, int n_in,
                              void* d_out, int out_size, void* d_ws, size_t ws_size,
                              hipStream_t stream) {
    const int*   neighs     = (const int*)d_in[0];
    const float* hier       = (const float*)d_in[1];
    const int*   row_splits = (const int*)d_in[2];

    const int V    = in_sizes[1];
    const int K    = in_sizes[0] / V;
    const int NSEG = in_sizes[2] - 1;
    const long E   = (long)V * (long)K;

    int* out      = (int*)d_out;
    int* sel_out  = out;
    int* rs_out   = out + V;
    int* clus_out = out + V + NSEG + 1;

    // ws: [best 8V][word 4V][cnts 128][rsBase 128][segKeys 8V][segIds 4V][cidOf 4V]
    char* w = (char*)d_ws;
    ull*      best    = (ull*)(w);
    unsigned* word    = (unsigned*)(w + (size_t)8 * V);
    int*      cnts    = (int*)(w + (size_t)12 * V);
    int*      rsBase  = (int*)(w + (size_t)12 * V + 128);
    size_t segOff     = (size_t)12 * V + 256;
    ull*      segKeys = (ull*)(w + segOff);
    int*      segIds  = (int*)(w + segOff + (size_t)8 * V);
    int*      cidOf   = (int*)(w + segOff + (size_t)12 * V);

    const int B  = 256;
    const int gV = (V + B - 1) / B;

    (void)hipMemsetAsync(w, 0, segOff, stream);               // best, word, cnts
    (void)hipMemsetAsync(sel_out, 0xFF, (size_t)4 * V, stream);

    if ((K & 3) == 0) {
        long E4 = E / 4;
        k_build4<<<(int)((E4 + B - 1) / B), B, 0, stream>>>(neighs, hier, word, E4, K);
    } else {
        k_build1<<<(int)((E + B - 1) / B), B, 0, stream>>>(neighs, hier, word, E, K);
    }

    const int PB = 1024;                 // 4 blocks/CU co-resident
    const int NW = PB * B / 64;          // 4096 waves; each owns <=2 groups of 64
    k_propagate<<<PB, B, 0, stream>>>(neighs, hier, word, V, K, NW);

    k_absorb<<<PB, B, 0, stream>>>(neighs, hier, word, best, V, K, NW);
    k_compact<<<gV, B, 0, stream>>>(hier, word, row_splits, segKeys, segIds, cnts, V, NSEG);
    k_rs<<<1, 64, 0, stream>>>(cnts, rsBase, rs_out, NSEG);
    k_rank<<<gV, B, 0, stream>>>(segKeys, segIds, cnts, rsBase, row_splits,
                                 cidOf, sel_out, V, NSEG);
    k_assign<<<gV, B, 0, stream>>>(best, cidOf, clus_out, V);
}

// Round 14
// 1288.361 us; speedup vs baseline: 133.4265x; 1.3635x over previous
//
#include <hip/hip_runtime.h>
#include <stdint.h>

typedef unsigned long long ull;

static __device__ __forceinline__ ull packkey(float f, int v) {
    uint32_t u = __float_as_uint(f);
    u = (u & 0x80000000u) ? ~u : (u | 0x80000000u);
    return ((ull)u << 32) | (ull)(~(uint32_t)v);
}
static __device__ __forceinline__ unsigned aloadu32(const unsigned* p) {
    return __hip_atomic_load(p, __ATOMIC_RELAXED, __HIP_MEMORY_SCOPE_AGENT);
}

// ---------------- build: in-degree of absorption DAG into pred field (word>>16) ----------------
__global__ void k_build4(const int* __restrict__ neighs, const float* __restrict__ hier,
                         unsigned* __restrict__ word, long E4, int K) {
    long t = (long)blockIdx.x * blockDim.x + threadIdx.x;
    if (t >= E4) return;
    long e = t * 4;
    int u = (int)(e / K);
    ull ku = packkey(hier[u], u);
    int4 w4 = *(const int4*)(neighs + e);
    int ws[4] = {w4.x, w4.y, w4.z, w4.w};
    #pragma unroll
    for (int j = 0; j < 4; j++) {
        int w = ws[j];
        if (w < 0) continue;
        if (ku > packkey(hier[w], w))
            atomicAdd(&word[w], 0x10000u);     // fire-and-forget
    }
}
__global__ void k_build1(const int* __restrict__ neighs, const float* __restrict__ hier,
                         unsigned* __restrict__ word, long E, int K) {
    long e = (long)blockIdx.x * blockDim.x + threadIdx.x;
    if (e >= E) return;
    int w = neighs[e];
    if (w < 0) return;
    int u = (int)(e / K);
    if (packkey(hier[u], u) > packkey(hier[w], w))
        atomicAdd(&word[w], 0x10000u);
}

// ---------------- propagation: owner polls word; fire-and-forget fused adds ----------------
// word[v] = pred<<16 | cenCount.  ABSORBED: cen>0.  CENTER: word==0.
static __device__ __forceinline__ bool sweep_group(
    int gb, bool pend, int lane,
    const int* __restrict__ neighs, const float* __restrict__ hier,
    unsigned* __restrict__ word, int K, bool& found)
{
    if (!__any(pend)) return pend;
    int v = gb + lane;
    unsigned wd = 0x7FFF0000u;
    if (pend) wd = aloadu32(&word[v]);
    bool absn = pend && ((wd & 0xFFFFu) != 0u);
    bool cenn = pend && (wd == 0u);
    bool dec = absn || cenn;
    ull mdec = __ballot(dec);
    if (!mdec) return pend;
    found = true;
    ull mcen = __ballot(cenn);

    while (mdec) {
        int ls[4];
        int nb = 0;
        while (nb < 4 && mdec) {
            int l = __ffsll((unsigned long long)mdec) - 1;
            mdec &= mdec - 1;
            ls[nb++] = l;
        }
        #pragma unroll
        for (int j = nb; j < 4; j++) ls[j] = -1;

        int vv[4]; ull kv[4]; unsigned dj[4];
        #pragma unroll
        for (int j = 0; j < 4; j++) {
            vv[j] = 0; kv[j] = 0; dj[j] = 0;
            if (ls[j] >= 0) {
                vv[j] = gb + ls[j];
                dj[j] = ((mcen >> ls[j]) & 1ull) ? 0xFFFF0001u : 0xFFFF0000u;
                kv[j] = packkey(hier[vv[j]], vv[j]);
            }
        }
        for (int k0 = 0; k0 < K; k0 += 64) {
            int k = k0 + lane;
            bool kok = k < K;
            #pragma unroll
            for (int j = 0; j < 4; j++) {
                if (ls[j] >= 0 && kok) {
                    int w = neighs[(size_t)vv[j] * (size_t)K + k];
                    if (w >= 0 && kv[j] > packkey(hier[w], w))
                        atomicAdd(&word[w], dj[j]);   // fused pred-release + cen-mark
                }
            }
        }
    }
    return pend && !dec;
}

__global__ __launch_bounds__(256, 4)
void k_propagate(const int* __restrict__ neighs, const float* __restrict__ hier,
                 unsigned* __restrict__ word, int V, int K, int nwaves) {
    const int gtid = blockIdx.x * blockDim.x + threadIdx.x;
    const int wv = gtid >> 6, lane = gtid & 63;
    const int G = (V + 63) >> 6;
    int gb0 = (wv < G) ? (wv << 6) : -1;
    int g1 = wv + nwaves;
    int gb1 = (g1 < G) ? (g1 << 6) : -1;
    bool p0 = gb0 >= 0 && gb0 + lane < V;
    bool p1 = gb1 >= 0 && gb1 + lane < V;

    long sweeps = 0;
    while (__any(p0 || p1)) {
        bool found = false;
        p0 = sweep_group(gb0, p0, lane, neighs, hier, word, K, found);
        p1 = sweep_group(gb1, p1, lane, neighs, hier, word, K, found);
        if (found) {
            sweeps = 0;
        } else {
            __builtin_amdgcn_s_sleep(2);
            if (++sweeps > 1000000L) break;   // safety net: never hang the bench
        }
    }
}

// ---------------- epilogue: absorber identity = max key over centers containing w ----------------
__global__ void k_absorb(const int* __restrict__ neighs, const float* __restrict__ hier,
                         const unsigned* __restrict__ word, ull* __restrict__ best,
                         int V, int K, int NW) {
    const int gtid = blockIdx.x * blockDim.x + threadIdx.x;
    const int wv = gtid >> 6, lane = gtid & 63;
    const int G = (V + 63) >> 6;
    for (int g = wv; g < G; g += NW) {
        int v = (g << 6) + lane;
        bool cenv = (v < V) && ((word[v] & 0xFFFFu) == 0u);
        ull cm = __ballot(cenv);
        while (cm) {
            int l = __ffsll((unsigned long long)cm) - 1;
            cm &= cm - 1;
            int u = (g << 6) + l;
            ull ku = packkey(hier[u], u);
            const int* row = neighs + (size_t)u * (size_t)K;
            for (int k0 = 0; k0 < K; k0 += 64) {
                int k = k0 + lane;
                int w = (k < K) ? row[k] : -1;
                if (w >= 0 && ku > packkey(hier[w], w))
                    atomicMax(&best[w], ku);
            }
        }
    }
}

// ---------------- compact centers per segment (ballot-batched) ----------------
__global__ void k_compact(const float* __restrict__ hier,
                          const unsigned* __restrict__ word,
                          const int* __restrict__ row_splits,
                          ull* __restrict__ segKeys,
                          int* __restrict__ segIds,
                          int* __restrict__ counters,
                          int V, int NSEG) {
    int v = blockIdx.x * blockDim.x + threadIdx.x;
    int lane = threadIdx.x & 63;
    bool isc = (v < V) && ((word[v] & 0xFFFFu) == 0u);
    int s = 0;
    if (isc) { while (s + 1 < NSEG && v >= row_splits[s + 1]) s++; }
    if (!__any(isc)) return;
    for (int s0 = 0; s0 < NSEG; s0++) {
        ull ms = __ballot(isc && s == s0);
        if (!ms) continue;
        int leader = __ffsll((unsigned long long)ms) - 1;
        int n = __popcll(ms);
        unsigned base = 0;
        if (lane == leader) base = (unsigned)atomicAdd(&counters[s0], n);
        base = (unsigned)__shfl((int)base, leader);
        unsigned pre = (unsigned)__popcll(ms & ((1ull << lane) - 1ull));
        if (isc && s == s0) {
            int slot = row_splits[s0] + (int)(base + pre);
            segKeys[slot] = packkey(hier[v], v);
            segIds[slot] = v;
        }
    }
}

// ---------------- rs prefix (tiny) ----------------
__global__ void k_rs(const int* __restrict__ counters,
                     int* __restrict__ rsBase,
                     int* __restrict__ rs_out,
                     int NSEG) {
    if (blockIdx.x == 0 && threadIdx.x == 0) {
        int acc = 0;
        rs_out[0] = 0;
        for (int s = 0; s < NSEG; s++) {
            rsBase[s] = acc;
            acc += counters[s];
            rs_out[s + 1] = acc;
        }
    }
}

// ---------------- rank centers -> cid, sel: LDS-tiled broadcast O(n^2) ----------------
#define RTILE 1024
__global__ void k_rank(const ull* __restrict__ segKeys,
                       const int* __restrict__ segIds,
                       const int* __restrict__ counters,
                       const int* __restrict__ rsBase,
                       const int* __restrict__ row_splits,
                       int* __restrict__ cidOf,
                       int* __restrict__ sel_out,
                       int V, int NSEG) {
    __shared__ ull tile[RTILE];
    int t = blockIdx.x * blockDim.x + threadIdx.x;   // slot index
    int s = 0;
    if (t < V) { while (s + 1 < NSEG && t >= row_splits[s + 1]) s++; }
    int base = (t < V) ? row_splits[s] : 0;
    int j = (t < V) ? (t - base) : -1;
    int cnt = (t < V) ? counters[s] : 0;
    bool active = (t < V) && (j >= 0) && (j < cnt);
    ull mk = active ? segKeys[t] : 0ull;
    int r = 0;

    // block's slot range spans <=2 segments; uniform per block
    int B0 = blockIdx.x * blockDim.x;
    int B1 = min(B0 + (int)blockDim.x - 1, V - 1);
    int sf = 0; while (sf + 1 < NSEG && B0 >= row_splits[sf + 1]) sf++;
    int sl = 0; while (sl + 1 < NSEG && B1 >= row_splits[sl + 1]) sl++;

    for (int s0 = sf; s0 <= sl; s0++) {
        int b0 = row_splits[s0];
        int c0 = counters[s0];
        bool in = active && (s == s0);
        for (int tb = 0; tb < c0; tb += RTILE) {
            int n = min(RTILE, c0 - tb);
            __syncthreads();
            for (int i = threadIdx.x; i < n; i += blockDim.x)
                tile[i] = segKeys[b0 + tb + i];
            __syncthreads();
            if (in) {
                int rr = 0;
                #pragma unroll 8
                for (int i = 0; i < n; i++) rr += (tile[i] > mk) ? 1 : 0;
                r += rr;
            }
        }
    }
    if (active) {
        int cid = rsBase[s] + r;
        int v = segIds[t];
        cidOf[v] = cid;
        sel_out[cid] = v;
    }
}

// ---------------- final cluster assignment ----------------
__global__ void k_assign(const ull* __restrict__ best,
                         const int* __restrict__ cidOf,
                         int* __restrict__ clus_out,
                         int V) {
    int v = blockIdx.x * blockDim.x + threadIdx.x;
    if (v >= V) return;
    ull b = best[v];
    int c;
    if (b == 0ull) {
        c = cidOf[v];                                   // center (never receives a max)
    } else {
        uint32_t a = ~(uint32_t)(b & 0xFFFFFFFFull);    // absorber global index
        c = cidOf[a];
    }
    clus_out[v] = c;
}

extern "C" void kernel_launch(void* const* d_in, const int* in_sizes, int n_in,
                              void* d_out, int out_size, void* d_ws, size_t ws_size,
                              hipStream_t stream) {
    const int*   neighs     = (const int*)d_in[0];
    const float* hier       = (const float*)d_in[1];
    const int*   row_splits = (const int*)d_in[2];

    const int V    = in_sizes[1];
    const int K    = in_sizes[0] / V;
    const int NSEG = in_sizes[2] - 1;
    const long E   = (long)V * (long)K;

    int* out      = (int*)d_out;
    int* sel_out  = out;
    int* rs_out   = out + V;
    int* clus_out = out + V + NSEG + 1;

    // ws: [best 8V][word 4V][cnts 128][rsBase 128][segKeys 8V][segIds 4V][cidOf 4V]
    char* w = (char*)d_ws;
    ull*      best    = (ull*)(w);
    unsigned* word    = (unsigned*)(w + (size_t)8 * V);
    int*      cnts    = (int*)(w + (size_t)12 * V);
    int*      rsBase  = (int*)(w + (size_t)12 * V + 128);
    size_t segOff     = (size_t)12 * V + 256;
    ull*      segKeys = (ull*)(w + segOff);
    int*      segIds  = (int*)(w + segOff + (size_t)8 * V);
    int*      cidOf   = (int*)(w + segOff + (size_t)12 * V);

    const int B  = 256;
    const int gV = (V + B - 1) / B;

    (void)hipMemsetAsync(w, 0, segOff, stream);               // best, word, cnts
    (void)hipMemsetAsync(sel_out, 0xFF, (size_t)4 * V, stream);

    if ((K & 3) == 0) {
        long E4 = E / 4;
        k_build4<<<(int)((E4 + B - 1) / B), B, 0, stream>>>(neighs, hier, word, E4, K);
    } else {
        k_build1<<<(int)((E + B - 1) / B), B, 0, stream>>>(neighs, hier, word, E, K);
    }

    const int PB = 1024;                 // 4 blocks/CU co-resident
    const int NW = PB * B / 64;          // 4096 waves; each owns <=2 groups of 64
    k_propagate<<<PB, B, 0, stream>>>(neighs, hier, word, V, K, NW);

    k_absorb<<<PB, B, 0, stream>>>(neighs, hier, word, best, V, K, NW);
    k_compact<<<gV, B, 0, stream>>>(hier, word, row_splits, segKeys, segIds, cnts, V, NSEG);
    k_rs<<<1, 64, 0, stream>>>(cnts, rsBase, rs_out, NSEG);
    k_rank<<<gV, B, 0, stream>>>(segKeys, segIds, cnts, rsBase, row_splits,
                                 cidOf, sel_out, V, NSEG);
    k_assign<<<gV, B, 0, stream>>>(best, cidOf, clus_out, V);
}

// Round 15
// 1284.334 us; speedup vs baseline: 133.8447x; 1.0031x over previous
//
#include <hip/hip_runtime.h>
#include <stdint.h>

typedef unsigned long long ull;

static __device__ __forceinline__ ull packkey(float f, int v) {
    uint32_t u = __float_as_uint(f);
    u = (u & 0x80000000u) ? ~u : (u | 0x80000000u);
    return ((ull)u << 32) | (ull)(~(uint32_t)v);
}
static __device__ __forceinline__ unsigned aloadu32(const unsigned* p) {
    return __hip_atomic_load(p, __ATOMIC_RELAXED, __HIP_MEMORY_SCOPE_AGENT);
}

// ---------------- build: in-degree of absorption DAG into pred field (word>>16) ----------------
__global__ void k_build4(const int* __restrict__ neighs, const float* __restrict__ hier,
                         unsigned* __restrict__ word, long E4, int K) {
    long t = (long)blockIdx.x * blockDim.x + threadIdx.x;
    if (t >= E4) return;
    long e = t * 4;
    int u = (int)(e / K);
    ull ku = packkey(hier[u], u);
    int4 w4 = *(const int4*)(neighs + e);
    int ws[4] = {w4.x, w4.y, w4.z, w4.w};
    #pragma unroll
    for (int j = 0; j < 4; j++) {
        int w = ws[j];
        if (w < 0) continue;
        if (ku > packkey(hier[w], w))
            atomicAdd(&word[w], 0x10000u);     // fire-and-forget
    }
}
__global__ void k_build1(const int* __restrict__ neighs, const float* __restrict__ hier,
                         unsigned* __restrict__ word, long E, int K) {
    long e = (long)blockIdx.x * blockDim.x + threadIdx.x;
    if (e >= E) return;
    int w = neighs[e];
    if (w < 0) return;
    int u = (int)(e / K);
    if (packkey(hier[u], u) > packkey(hier[w], w))
        atomicAdd(&word[w], 0x10000u);
}

// ---------------- propagation: owner polls word; fused adds + center maxes ----------------
// word[v] = pred<<16 | cenCount.  ABSORBED: cen>0.  CENTER: word==0.
// Centers also fire atomicMax(best[w], kv) — fire-and-forget, NO fence needed:
// best is only read by k_assign after this kernel retires (kernel-boundary ordering).
static __device__ __forceinline__ bool sweep_group(
    int gb, bool pend, int lane,
    const int* __restrict__ neighs, const float* __restrict__ hier,
    unsigned* __restrict__ word, ull* __restrict__ best, int K, bool& found)
{
    if (!__any(pend)) return pend;
    int v = gb + lane;
    unsigned wd = 0x7FFF0000u;
    if (pend) wd = aloadu32(&word[v]);
    bool absn = pend && ((wd & 0xFFFFu) != 0u);
    bool cenn = pend && (wd == 0u);
    bool dec = absn || cenn;
    ull mdec = __ballot(dec);
    if (!mdec) return pend;
    found = true;
    ull mcen = __ballot(cenn);

    while (mdec) {
        int ls[4];
        int nb = 0;
        while (nb < 4 && mdec) {
            int l = __ffsll((unsigned long long)mdec) - 1;
            mdec &= mdec - 1;
            ls[nb++] = l;
        }
        #pragma unroll
        for (int j = nb; j < 4; j++) ls[j] = -1;

        int vv[4]; ull kv[4]; unsigned dj[4]; bool cj[4];
        #pragma unroll
        for (int j = 0; j < 4; j++) {
            vv[j] = 0; kv[j] = 0; dj[j] = 0; cj[j] = false;
            if (ls[j] >= 0) {
                vv[j] = gb + ls[j];
                cj[j] = (mcen >> ls[j]) & 1ull;
                dj[j] = cj[j] ? 0xFFFF0001u : 0xFFFF0000u;
                kv[j] = packkey(hier[vv[j]], vv[j]);
            }
        }
        for (int k0 = 0; k0 < K; k0 += 64) {
            int k = k0 + lane;
            bool kok = k < K;
            #pragma unroll
            for (int j = 0; j < 4; j++) {
                if (ls[j] >= 0 && kok) {
                    int w = neighs[(size_t)vv[j] * (size_t)K + k];
                    if (w >= 0 && kv[j] > packkey(hier[w], w)) {
                        atomicAdd(&word[w], dj[j]);          // fused pred-release + cen-mark
                        if (cj[j]) atomicMax(&best[w], kv[j]); // absorber record (fused absorb)
                    }
                }
            }
        }
    }
    return pend && !dec;
}

__global__ __launch_bounds__(256, 8)
void k_propagate(const int* __restrict__ neighs, const float* __restrict__ hier,
                 unsigned* __restrict__ word, ull* __restrict__ best,
                 int V, int K, int nwaves) {
    const int gtid = blockIdx.x * blockDim.x + threadIdx.x;
    const int wv = gtid >> 6, lane = gtid & 63;
    const int G = (V + 63) >> 6;
    int gb0 = (wv < G) ? (wv << 6) : -1;
    int g1 = wv + nwaves;
    int gb1 = (g1 < G) ? (g1 << 6) : -1;
    bool p0 = gb0 >= 0 && gb0 + lane < V;
    bool p1 = gb1 >= 0 && gb1 + lane < V;

    long sweeps = 0;
    while (__any(p0 || p1)) {
        bool found = false;
        p0 = sweep_group(gb0, p0, lane, neighs, hier, word, best, K, found);
        p1 = sweep_group(gb1, p1, lane, neighs, hier, word, best, K, found);
        if (found) {
            sweeps = 0;
        } else {
            __builtin_amdgcn_s_sleep(2);
            if (++sweeps > 2000000L) break;   // safety net: never hang the bench
        }
    }
}

// ---------------- compact centers per segment (ballot-batched) ----------------
__global__ void k_compact(const float* __restrict__ hier,
                          const unsigned* __restrict__ word,
                          const int* __restrict__ row_splits,
                          ull* __restrict__ segKeys,
                          int* __restrict__ segIds,
                          int* __restrict__ counters,
                          int V, int NSEG) {
    int v = blockIdx.x * blockDim.x + threadIdx.x;
    int lane = threadIdx.x & 63;
    bool isc = (v < V) && ((word[v] & 0xFFFFu) == 0u);
    int s = 0;
    if (isc) { while (s + 1 < NSEG && v >= row_splits[s + 1]) s++; }
    if (!__any(isc)) return;
    for (int s0 = 0; s0 < NSEG; s0++) {
        ull ms = __ballot(isc && s == s0);
        if (!ms) continue;
        int leader = __ffsll((unsigned long long)ms) - 1;
        int n = __popcll(ms);
        unsigned base = 0;
        if (lane == leader) base = (unsigned)atomicAdd(&counters[s0], n);
        base = (unsigned)__shfl((int)base, leader);
        unsigned pre = (unsigned)__popcll(ms & ((1ull << lane) - 1ull));
        if (isc && s == s0) {
            int slot = row_splits[s0] + (int)(base + pre);
            segKeys[slot] = packkey(hier[v], v);
            segIds[slot] = v;
        }
    }
}

// ---------------- rs prefix (tiny) ----------------
__global__ void k_rs(const int* __restrict__ counters,
                     int* __restrict__ rsBase,
                     int* __restrict__ rs_out,
                     int NSEG) {
    if (blockIdx.x == 0 && threadIdx.x == 0) {
        int acc = 0;
        rs_out[0] = 0;
        for (int s = 0; s < NSEG; s++) {
            rsBase[s] = acc;
            acc += counters[s];
            rs_out[s + 1] = acc;
        }
    }
}

// ---------------- rank centers -> cid, sel: LDS-tiled broadcast O(n^2) ----------------
#define RTILE 1024
__global__ void k_rank(const ull* __restrict__ segKeys,
                       const int* __restrict__ segIds,
                       const int* __restrict__ counters,
                       const int* __restrict__ rsBase,
                       const int* __restrict__ row_splits,
                       int* __restrict__ cidOf,
                       int* __restrict__ sel_out,
                       int V, int NSEG) {
    __shared__ ull tile[RTILE];
    int t = blockIdx.x * blockDim.x + threadIdx.x;   // slot index
    int s = 0;
    if (t < V) { while (s + 1 < NSEG && t >= row_splits[s + 1]) s++; }
    int base = (t < V) ? row_splits[s] : 0;
    int j = (t < V) ? (t - base) : -1;
    int cnt = (t < V) ? counters[s] : 0;
    bool active = (t < V) && (j >= 0) && (j < cnt);
    ull mk = active ? segKeys[t] : 0ull;
    int r = 0;

    // block's slot range spans <=2 segments; uniform per block
    int B0 = blockIdx.x * blockDim.x;
    int B1 = min(B0 + (int)blockDim.x - 1, V - 1);
    int sf = 0; while (sf + 1 < NSEG && B0 >= row_splits[sf + 1]) sf++;
    int sl = 0; while (sl + 1 < NSEG && B1 >= row_splits[sl + 1]) sl++;

    for (int s0 = sf; s0 <= sl; s0++) {
        int b0 = row_splits[s0];
        int c0 = counters[s0];
        bool in = active && (s == s0);
        for (int tb = 0; tb < c0; tb += RTILE) {
            int n = min(RTILE, c0 - tb);
            __syncthreads();
            for (int i = threadIdx.x; i < n; i += blockDim.x)
                tile[i] = segKeys[b0 + tb + i];
            __syncthreads();
            if (in) {
                int rr = 0;
                #pragma unroll 8
                for (int i = 0; i < n; i++) rr += (tile[i] > mk) ? 1 : 0;
                r += rr;
            }
        }
    }
    if (active) {
        int cid = rsBase[s] + r;
        int v = segIds[t];
        cidOf[v] = cid;
        sel_out[cid] = v;
    }
}

// ---------------- final cluster assignment ----------------
__global__ void k_assign(const ull* __restrict__ best,
                         const int* __restrict__ cidOf,
                         int* __restrict__ clus_out,
                         int V) {
    int v = blockIdx.x * blockDim.x + threadIdx.x;
    if (v >= V) return;
    ull b = best[v];
    int c;
    if (b == 0ull) {
        c = cidOf[v];                                   // center (never receives a max)
    } else {
        uint32_t a = ~(uint32_t)(b & 0xFFFFFFFFull);    // absorber global index
        c = cidOf[a];
    }
    clus_out[v] = c;
}

extern "C" void kernel_launch(void* const* d_in, const int* in_sizes, int n_in,
                              void* d_out, int out_size, void* d_ws, size_t ws_size,
                              hipStream_t stream) {
    const int*   neighs     = (const int*)d_in[0];
    const float* hier       = (const float*)d_in[1];
    const int*   row_splits = (const int*)d_in[2];

    const int V    = in_sizes[1];
    const int K    = in_sizes[0] / V;
    const int NSEG = in_sizes[2] - 1;
    const long E   = (long)V * (long)K;

    int* out      = (int*)d_out;
    int* sel_out  = out;
    int* rs_out   = out + V;
    int* clus_out = out + V + NSEG + 1;

    // ws: [best 8V][word 4V][cnts 128][rsBase 128][segKeys 8V][segIds 4V][cidOf 4V]
    char* w = (char*)d_ws;
    ull*      best    = (ull*)(w);
    unsigned* word    = (unsigned*)(w + (size_t)8 * V);
    int*      cnts    = (int*)(w + (size_t)12 * V);
    int*      rsBase  = (int*)(w + (size_t)12 * V + 128);
    size_t segOff     = (size_t)12 * V + 256;
    ull*      segKeys = (ull*)(w + segOff);
    int*      segIds  = (int*)(w + segOff + (size_t)8 * V);
    int*      cidOf   = (int*)(w + segOff + (size_t)12 * V);

    const int B  = 256;
    const int gV = (V + B - 1) / B;

    (void)hipMemsetAsync(w, 0, segOff, stream);               // best, word, cnts
    (void)hipMemsetAsync(sel_out, 0xFF, (size_t)4 * V, stream);

    if ((K & 3) == 0) {
        long E4 = E / 4;
        k_build4<<<(int)((E4 + B - 1) / B), B, 0, stream>>>(neighs, hier, word, E4, K);
    } else {
        k_build1<<<(int)((E + B - 1) / B), B, 0, stream>>>(neighs, hier, word, E, K);
    }

    const int PB = 2048;                 // 8 blocks/CU co-resident (VGPR ~20)
    const int NW = PB * B / 64;          // 8192 waves; each owns <=1 group of 64
    k_propagate<<<PB, B, 0, stream>>>(neighs, hier, word, best, V, K, NW);

    k_compact<<<gV, B, 0, stream>>>(hier, word, row_splits, segKeys, segIds, cnts, V, NSEG);
    k_rs<<<1, 64, 0, stream>>>(cnts, rsBase, rs_out, NSEG);
    k_rank<<<gV, B, 0, stream>>>(segKeys, segIds, cnts, rsBase, row_splits,
                                 cidOf, sel_out, V, NSEG);
    k_assign<<<gV, B, 0, stream>>>(best, cidOf, clus_out, V);
}

// Round 16
// 1284.307 us; speedup vs baseline: 133.8476x; 1.0000x over previous
//
#include <hip/hip_runtime.h>
#include <stdint.h>

typedef unsigned long long ull;

static __device__ __forceinline__ ull packkey(float f, int v) {
    uint32_t u = __float_as_uint(f);
    u = (u & 0x80000000u) ? ~u : (u | 0x80000000u);
    return ((ull)u << 32) | (ull)(~(uint32_t)v);
}
static __device__ __forceinline__ unsigned aloadu32(const unsigned* p) {
    return __hip_atomic_load(p, __ATOMIC_RELAXED, __HIP_MEMORY_SCOPE_AGENT);
}

// ---------------- build: in-degree of absorption DAG into pred field (word>>16) ----------------
__global__ void k_build4(const int* __restrict__ neighs, const float* __restrict__ hier,
                         unsigned* __restrict__ word, long E4, int K) {
    long t = (long)blockIdx.x * blockDim.x + threadIdx.x;
    if (t >= E4) return;
    long e = t * 4;
    int u = (int)(e / K);
    ull ku = packkey(hier[u], u);
    int4 w4 = *(const int4*)(neighs + e);
    int ws[4] = {w4.x, w4.y, w4.z, w4.w};
    #pragma unroll
    for (int j = 0; j < 4; j++) {
        int w = ws[j];
        if (w < 0) continue;
        if (ku > packkey(hier[w], w))
            atomicAdd(&word[w], 0x10000u);     // fire-and-forget
    }
}
__global__ void k_build1(const int* __restrict__ neighs, const float* __restrict__ hier,
                         unsigned* __restrict__ word, long E, int K) {
    long e = (long)blockIdx.x * blockDim.x + threadIdx.x;
    if (e >= E) return;
    int w = neighs[e];
    if (w < 0) return;
    int u = (int)(e / K);
    if (packkey(hier[u], u) > packkey(hier[w], w))
        atomicAdd(&word[w], 0x10000u);
}

// ---------------- propagation: owner polls word; fused adds + center maxes ----------------
// word[v] = pred<<16 | cenCount.  ABSORBED: cen>0.  CENTER: word==0.
// Each wave owns exactly ONE 64-vertex group (grid sized so nwaves >= G).
__global__ __launch_bounds__(256, 8)
void k_propagate(const int* __restrict__ neighs, const float* __restrict__ hier,
                 unsigned* __restrict__ word, ull* __restrict__ best,
                 int V, int K) {
    const int gtid = blockIdx.x * blockDim.x + threadIdx.x;
    const int wv = gtid >> 6, lane = gtid & 63;
    const int gb = wv << 6;
    if (gb >= V) return;                     // wave owns nothing; exit immediately
    int v = gb + lane;
    bool pend = v < V;

    long sweeps = 0;
    while (__any(pend)) {
        unsigned wd = 0x7FFF0000u;
        if (pend) wd = aloadu32(&word[v]);
        bool absn = pend && ((wd & 0xFFFFu) != 0u);
        bool cenn = pend && (wd == 0u);
        bool dec = absn || cenn;
        ull mdec = __ballot(dec);
        if (!mdec) {
            __builtin_amdgcn_s_sleep(2);
            if (++sweeps > 2000000L) break;  // safety net: never hang the bench
            continue;
        }
        sweeps = 0;
        ull mcen = __ballot(cenn);
        if (dec) pend = false;

        while (mdec) {
            int ls[4];
            int nb = 0;
            while (nb < 4 && mdec) {
                int l = __ffsll((unsigned long long)mdec) - 1;
                mdec &= mdec - 1;
                ls[nb++] = l;
            }
            #pragma unroll
            for (int j = nb; j < 4; j++) ls[j] = -1;

            int vv[4]; ull kv[4]; unsigned dj[4]; bool cj[4];
            #pragma unroll
            for (int j = 0; j < 4; j++) {
                vv[j] = 0; kv[j] = 0; dj[j] = 0; cj[j] = false;
                if (ls[j] >= 0) {
                    vv[j] = gb + ls[j];
                    cj[j] = (mcen >> ls[j]) & 1ull;
                    dj[j] = cj[j] ? 0xFFFF0001u : 0xFFFF0000u;
                    kv[j] = packkey(hier[vv[j]], vv[j]);
                }
            }
            for (int k0 = 0; k0 < K; k0 += 64) {
                int k = k0 + lane;
                bool kok = k < K;
                #pragma unroll
                for (int j = 0; j < 4; j++) {
                    if (ls[j] >= 0 && kok) {
                        int w = neighs[(size_t)vv[j] * (size_t)K + k];
                        if (w >= 0 && kv[j] > packkey(hier[w], w)) {
                            atomicAdd(&word[w], dj[j]);            // fused pred-release + cen-mark
                            if (cj[j]) atomicMax(&best[w], kv[j]); // absorber record
                        }
                    }
                }
            }
        }
    }
}

// ---------------- compact centers per segment (ballot-batched) ----------------
__global__ void k_compact(const float* __restrict__ hier,
                          const unsigned* __restrict__ word,
                          const int* __restrict__ row_splits,
                          ull* __restrict__ segKeys,
                          int* __restrict__ segIds,
                          int* __restrict__ counters,
                          int V, int NSEG) {
    int v = blockIdx.x * blockDim.x + threadIdx.x;
    int lane = threadIdx.x & 63;
    bool isc = (v < V) && ((word[v] & 0xFFFFu) == 0u);
    int s = 0;
    if (isc) { while (s + 1 < NSEG && v >= row_splits[s + 1]) s++; }
    if (!__any(isc)) return;
    for (int s0 = 0; s0 < NSEG; s0++) {
        ull ms = __ballot(isc && s == s0);
        if (!ms) continue;
        int leader = __ffsll((unsigned long long)ms) - 1;
        int n = __popcll(ms);
        unsigned base = 0;
        if (lane == leader) base = (unsigned)atomicAdd(&counters[s0], n);
        base = (unsigned)__shfl((int)base, leader);
        unsigned pre = (unsigned)__popcll(ms & ((1ull << lane) - 1ull));
        if (isc && s == s0) {
            int slot = row_splits[s0] + (int)(base + pre);
            segKeys[slot] = packkey(hier[v], v);
            segIds[slot] = v;
        }
    }
}

// ---------------- rank centers -> cid, sel (rs prefix computed inline; writes rs_out) ----------------
#define RTILE 1024
__global__ void k_rank(const ull* __restrict__ segKeys,
                       const int* __restrict__ segIds,
                       const int* __restrict__ counters,
                       const int* __restrict__ row_splits,
                       int* __restrict__ cidOf,
                       int* __restrict__ sel_out,
                       int* __restrict__ rs_out,
                       int V, int NSEG) {
    __shared__ ull tile[RTILE];
    // inline prefix of counters (NSEG tiny, uniform)
    int rsb = 0;
    int t = blockIdx.x * blockDim.x + threadIdx.x;   // slot index
    int s = 0;
    if (t < V) { while (s + 1 < NSEG && t >= row_splits[s + 1]) s++; }
    for (int i = 0; i < s; i++) rsb += counters[i];

    if (blockIdx.x == 0 && threadIdx.x == 0) {       // write new row_splits
        int acc = 0;
        rs_out[0] = 0;
        for (int i = 0; i < NSEG; i++) { acc += counters[i]; rs_out[i + 1] = acc; }
    }

    int base = (t < V) ? row_splits[s] : 0;
    int j = (t < V) ? (t - base) : -1;
    int cnt = (t < V) ? counters[s] : 0;
    bool active = (t < V) && (j >= 0) && (j < cnt);
    ull mk = active ? segKeys[t] : 0ull;
    int r = 0;

    // block's slot range spans <=2 segments; uniform per block
    int B0 = blockIdx.x * blockDim.x;
    int B1 = min(B0 + (int)blockDim.x - 1, V - 1);
    int sf = 0; while (sf + 1 < NSEG && B0 >= row_splits[sf + 1]) sf++;
    int sl = 0; while (sl + 1 < NSEG && B1 >= row_splits[sl + 1]) sl++;

    for (int s0 = sf; s0 <= sl; s0++) {
        int b0 = row_splits[s0];
        int c0 = counters[s0];
        bool in = active && (s == s0);
        for (int tb = 0; tb < c0; tb += RTILE) {
            int n = min(RTILE, c0 - tb);
            __syncthreads();
            for (int i = threadIdx.x; i < n; i += blockDim.x)
                tile[i] = segKeys[b0 + tb + i];
            __syncthreads();
            if (in) {
                int rr = 0;
                #pragma unroll 8
                for (int i = 0; i < n; i++) rr += (tile[i] > mk) ? 1 : 0;
                r += rr;
            }
        }
    }
    if (active) {
        int cid = rsb + r;
        int v = segIds[t];
        cidOf[v] = cid;
        sel_out[cid] = v;
    }
}

// ---------------- final cluster assignment ----------------
__global__ void k_assign(const ull* __restrict__ best,
                         const int* __restrict__ cidOf,
                         int* __restrict__ clus_out,
                         int V) {
    int v = blockIdx.x * blockDim.x + threadIdx.x;
    if (v >= V) return;
    ull b = best[v];
    int c;
    if (b == 0ull) {
        c = cidOf[v];                                   // center (never receives a max)
    } else {
        uint32_t a = ~(uint32_t)(b & 0xFFFFFFFFull);    // absorber global index
        c = cidOf[a];
    }
    clus_out[v] = c;
}

extern "C" void kernel_launch(void* const* d_in, const int* in_sizes, int n_in,
                              void* d_out, int out_size, void* d_ws, size_t ws_size,
                              hipStream_t stream) {
    const int*   neighs     = (const int*)d_in[0];
    const float* hier       = (const float*)d_in[1];
    const int*   row_splits = (const int*)d_in[2];

    const int V    = in_sizes[1];
    const int K    = in_sizes[0] / V;
    const int NSEG = in_sizes[2] - 1;
    const long E   = (long)V * (long)K;

    int* out      = (int*)d_out;
    int* sel_out  = out;
    int* rs_out   = out + V;
    int* clus_out = out + V + NSEG + 1;

    // ws: [best 8V][word 4V][cnts 128][segKeys 8V][segIds 4V][cidOf 4V]
    char* w = (char*)d_ws;
    ull*      best    = (ull*)(w);
    unsigned* word    = (unsigned*)(w + (size_t)8 * V);
    int*      cnts    = (int*)(w + (size_t)12 * V);
    size_t segOff     = (size_t)12 * V + 128;
    ull*      segKeys = (ull*)(w + segOff);
    int*      segIds  = (int*)(w + segOff + (size_t)8 * V);
    int*      cidOf   = (int*)(w + segOff + (size_t)12 * V);

    const int B  = 256;
    const int gV = (V + B - 1) / B;

    (void)hipMemsetAsync(w, 0, segOff, stream);               // best, word, cnts
    (void)hipMemsetAsync(sel_out, 0xFF, (size_t)4 * V, stream);

    if ((K & 3) == 0) {
        long E4 = E / 4;
        k_build4<<<(int)((E4 + B - 1) / B), B, 0, stream>>>(neighs, hier, word, E4, K);
    } else {
        k_build1<<<(int)((E + B - 1) / B), B, 0, stream>>>(neighs, hier, word, E, K);
    }

    const int G  = (V + 63) >> 6;        // 64-vertex groups
    const int PB = (G + 3) / 4;          // 4 waves/block -> every wave owns exactly one group
    k_propagate<<<PB, B, 0, stream>>>(neighs, hier, word, best, V, K);

    k_compact<<<gV, B, 0, stream>>>(hier, word, row_splits, segKeys, segIds, cnts, V, NSEG);
    k_rank<<<gV, B, 0, stream>>>(segKeys, segIds, cnts, row_splits,
                                 cidOf, sel_out, rs_out, V, NSEG);
    k_assign<<<gV, B, 0, stream>>>(best, cidOf, clus_out, V);
}